// Round 9
// baseline (103.594 us; speedup 1.0000x reference)
//
#include <hip/hip_runtime.h>

// SparseConv1x1 == GEMM: C[o,s] = W[o,:] . X[:,s] + b[o], s = n*784+hw
// M=1024, N=25088, K=1024, fp32 in/out, bf16 MFMA compute.
// Round 9: A-operand (W) fragment-packed in global (L2-hot, 2MB) -> loaded
// straight to MFMA regs, bypassing LDS. Halves LDS traffic (96->48KB/block-step).
// B path / x-prepass / epilogue byte-identical to round 8 (proven 26.5us + 0 conflicts).

#define IN_C   1024
#define OUT_C  1024
#define HW     784
#define NB     32
#define NHW    (NB * HW)                     // 25088
#define XT_BYTES ((size_t)NHW * IN_C * 2)    // 51,380,224
#define WB_BYTES ((size_t)OUT_C * IN_C * 2)  // 2,097,152
#define WS_NEEDED (XT_BYTES + WB_BYTES)
#define XSTR   (IN_C * HW)

typedef __bf16 bf16x8 __attribute__((ext_vector_type(8)));
typedef float  f32x4  __attribute__((ext_vector_type(4)));
typedef unsigned int u32x4 __attribute__((ext_vector_type(4)));

__device__ __forceinline__ unsigned int bfbits(float f) {
    unsigned int u = __float_as_uint(f);
    return (u + 0x8000u) >> 16;              // round-half-up fp32->bf16
}
__device__ __forceinline__ unsigned int packpair(float lo, float hi) {
    return bfbits(lo) | (bfbits(hi) << 16);
}
__device__ __forceinline__ void glds16(const void* g, void* l) {
    __builtin_amdgcn_global_load_lds(
        (const __attribute__((address_space(1))) void*)g,
        (__attribute__((address_space(3))) void*)l, 16, 0, 0);
}

// ---------- pre-pass: blocks [0,3136) transpose x; [3136,3648) W -> fragment-packed
// Wf layout: 16B unit at index ((rb*16 + c)*2 + kk)*64 + lane, where for source
// (o, u): rb=o>>4, c=u>>3, kk=(u>>2)&1, lane=(o&15)|((u&3)<<4).
// GEMM A-frag (fm,c,kk) is then one coalesced 1KB block read at base+lane*16.
__global__ __launch_bounds__(256)
void conv_pre(const float* __restrict__ X, const float* __restrict__ W,
              u32x4* __restrict__ Xt, u32x4* __restrict__ Wf)
{
    const int t = threadIdx.x;
    const int b = blockIdx.x;

    if (b >= 3136) {
        // W [1024][1024] f32 -> Wf bf16 fragment-packed
        int gid = (b - 3136) * 256 + t;
        int o = gid >> 7;
        int u = gid & 127;
        const float* p = W + o * 1024 + u * 8;
        f32x4 a = *(const f32x4*)p;
        f32x4 c4 = *(const f32x4*)(p + 4);
        u32x4 r;
        r.x = packpair(a[0], a[1]);  r.y = packpair(a[2], a[3]);
        r.z = packpair(c4[0], c4[1]); r.w = packpair(c4[2], c4[3]);
        const int rb = o >> 4, cch = u >> 3, kk = (u >> 2) & 1;
        const int ln = (o & 15) | ((u & 3) << 4);
        Wf[(((rb * 16 + cch) * 2 + kk) << 6) + ln] = r;
        return;
    }

    // x-path (verbatim r8): block = (s-tile of 128, k-chunk of 64); 3136 = 196*16
    const int c8   = b & 15;
    const int sblk = b >> 4;
    const int kq8  = t & 7;
    const int sc   = t >> 3;
    const int sgl  = sblk * 128 + sc * 4;    // mult of 4; 784%4==0 -> same batch
    const int n    = sgl / HW, hw0 = sgl % HW;
    const float* xb = X + (size_t)n * XSTR + (size_t)(c8 * 64 + kq8 * 8) * HW + hw0;

    f32x4 v[8];
#pragma unroll
    for (int i = 0; i < 8; ++i)
        v[i] = *(const f32x4*)(xb + (size_t)i * HW);

#pragma unroll
    for (int j = 0; j < 4; ++j) {
        u32x4 wv;
        wv.x = packpair(v[0][j], v[1][j]);
        wv.y = packpair(v[2][j], v[3][j]);
        wv.z = packpair(v[4][j], v[5][j]);
        wv.w = packpair(v[6][j], v[7][j]);
        const int sl = sgl + j;
        Xt[(size_t)sl * 128 + c8 * 8 + (kq8 ^ (sl & 7))] = wv;
    }
}

// ---------- GEMM: 128x128 tile, BK=64, 2-phase; A direct-from-global fragments ----
__global__ __launch_bounds__(256, 2)
void gemm_h(const char* __restrict__ Wf, const char* __restrict__ Xt,
            const float* __restrict__ Bias, float* __restrict__ Out)
{
    __shared__ __align__(16) char lB[128 * 128];  // B only: 16KB

    const int t = threadIdx.x, lane = t & 63, wid = t >> 6;
    const int wm = wid >> 1, wn = wid & 1;

    // XCD swizzle: 8 o-blocks of one s-tile contiguous within an XCD
    const int bid = blockIdx.x;                   // 1568 = 8*196
    const int l   = (bid & 7) * 196 + (bid >> 3);
    const int bo  = (l & 7) * 128;
    const int s0  = (l >> 3) * 128;

    // B staging (glds, verbatim r8)
    const char* bg = Xt + (size_t)(s0 + wid * 32 + (lane >> 3)) * 2048 + (lane & 7) * 16;
    char* lb0 = &lB[(wid * 32) * 128];

    // A fragment base: frag (fm, c, kk) at af_base + fm*32768 + c*2048 + kk*1024
    const char* af_base = Wf + (size_t)((bo >> 4) + wm * 4) * 32768 + (size_t)lane * 16;

    f32x4 acc[4][4];
#pragma unroll
    for (int i = 0; i < 4; ++i)
#pragma unroll
        for (int j = 0; j < 4; ++j) acc[i][j] = 0.0f;

    const int rsel = lane & 15, kg = lane >> 4;

    bf16x8 afA[8], afB[8];                        // ping-pong A frags [fm*2+kk]

#define LOADA(dst, c)                                                        \
    _Pragma("unroll")                                                        \
    for (int fm = 0; fm < 4; ++fm)                                           \
        _Pragma("unroll")                                                    \
        for (int kk = 0; kk < 2; ++kk)                                       \
            dst[fm * 2 + kk] = *(const bf16x8*)(af_base +                    \
                (size_t)fm * 32768 + (c) * 2048 + kk * 1024);

#define MFMA_STEP(cur, c)                                                    \
    _Pragma("unroll")                                                        \
    for (int kk = 0; kk < 2; ++kk) {                                         \
        bf16x8 bv[4];                                                        \
        _Pragma("unroll")                                                    \
        for (int fn = 0; fn < 4; ++fn) {                                     \
            const int row = wn * 64 + fn * 16 + rsel;                        \
            const int u   = (kk * 4 + kg) ^ (row & 7);                       \
            bv[fn] = *(const bf16x8*)&lB[row * 128 + u * 16];                \
        }                                                                    \
        _Pragma("unroll")                                                    \
        for (int fm = 0; fm < 4; ++fm)                                       \
            _Pragma("unroll")                                                \
            for (int fn = 0; fn < 4; ++fn)                                   \
                acc[fm][fn] = __builtin_amdgcn_mfma_f32_16x16x32_bf16(       \
                    cur[fm * 2 + kk], bv[fn], acc[fm][fn], 0, 0, 0);         \
    }

#define STEP(c, cur, nxt)                                                    \
    {                                                                        \
        _Pragma("unroll")                                                    \
        for (int i = 0; i < 4; ++i)                                          \
            glds16(bg + (size_t)i * (8 * 2048) + (c) * 128,                  \
                   lb0 + i * (8 * 128));                                     \
        __syncthreads();      /* B(c) + prior A landed */                    \
        if ((c) < 15) { LOADA(nxt, (c) + 1); }  /* drains under MFMA */      \
        MFMA_STEP(cur, c)                                                    \
        __syncthreads();      /* lB reads done; A(c+1) landed */             \
    }

    // prologue: A(0) issued first; drained by STEP(0)'s first barrier
    LOADA(afA, 0);

#pragma unroll 1
    for (int cc = 0; cc < 16; cc += 2) {
        STEP(cc,     afA, afB);
        STEP(cc + 1, afB, afA);
    }

    // epilogue: C/D layout col=lane&15, row=(lane>>4)*4+r; add bias
    const int ln15 = lane & 15, l4 = lane >> 4;
    int nidx[4], hwb[4];
#pragma unroll
    for (int fn = 0; fn < 4; ++fn) {
        int sb = s0 + wn * 64 + fn * 16;          // 784%16==0 -> same batch per 16-run
        nidx[fn] = sb / HW;
        hwb[fn]  = sb % HW;
    }
#pragma unroll
    for (int fm = 0; fm < 4; ++fm) {
#pragma unroll
        for (int r = 0; r < 4; ++r) {
            const int o = bo + wm * 64 + fm * 16 + l4 * 4 + r;
            const float bvs = Bias[o];
#pragma unroll
            for (int fn = 0; fn < 4; ++fn)
                Out[(size_t)nidx[fn] * (OUT_C * HW) + o * HW + hwb[fn] + ln15] =
                    acc[fm][fn][r] + bvs;
        }
    }
#undef STEP
#undef MFMA_STEP
#undef LOADA
}

// ---------- fallback (round-1 kernel, used only if ws too small) ----------
#define BM 128
#define BN 128
#define LDK 40
__global__ __launch_bounds__(256, 2)
void conv1x1_fallback(const float* __restrict__ X, const float* __restrict__ W,
                      const float* __restrict__ Bias, float* __restrict__ Out)
{
    __shared__ __align__(16) unsigned short lA[BM * LDK];
    __shared__ __align__(16) unsigned short lB[BN * LDK];
    const int t = threadIdx.x, lane = t & 63, wid = t >> 6;
    const int wm = wid >> 1, wn = wid & 1;
    const int s0 = blockIdx.x * BN, bo = blockIdx.y * BM;
    const int kc4 = t & 7, r0 = t >> 3;
    const float* aptr = W + (bo + r0) * IN_C + kc4 * 4;
    const int kp = t & 15, sc = t >> 4;
    const int sglob = s0 + sc * 8;
    const int nbat = sglob / HW, hw0 = sglob % HW;
    const float* bptr = X + nbat * (IN_C * HW) + hw0;
    f32x4 acc[4][4];
#pragma unroll
    for (int i = 0; i < 4; ++i)
#pragma unroll
        for (int j = 0; j < 4; ++j) acc[i][j] = 0.0f;
    for (int k0 = 0; k0 < IN_C; k0 += 32) {
        f32x4 a[4];
#pragma unroll
        for (int i = 0; i < 4; ++i) a[i] = *(const f32x4*)(aptr + (i * 32) * IN_C + k0);
        const float* bp = bptr + (k0 + 2 * kp) * HW;
        f32x4 be0 = *(const f32x4*)(bp), be1 = *(const f32x4*)(bp + 4);
        f32x4 bo0 = *(const f32x4*)(bp + HW), bo1 = *(const f32x4*)(bp + HW + 4);
        __syncthreads();
#pragma unroll
        for (int i = 0; i < 4; ++i) {
            unsigned int w0 = packpair(a[i][0], a[i][1]);
            unsigned int w1 = packpair(a[i][2], a[i][3]);
            unsigned long long pq = ((unsigned long long)w1 << 32) | w0;
            *(unsigned long long*)&lA[(r0 + 32 * i) * LDK + kc4 * 4] = pq;
        }
#pragma unroll
        for (int c2 = 0; c2 < 2; ++c2) {
            const f32x4 ve = (c2 == 0) ? be0 : be1;
            const f32x4 vo = (c2 == 0) ? bo0 : bo1;
#pragma unroll
            for (int j = 0; j < 4; ++j)
                *(unsigned int*)&lB[(sc * 8 + c2 * 4 + j) * LDK + 2 * kp] = packpair(ve[j], vo[j]);
        }
        __syncthreads();
        bf16x8 af[4], bfr[4];
        const int rsel = lane & 15, kgp = (lane >> 4) * 8;
#pragma unroll
        for (int fm = 0; fm < 4; ++fm)
            af[fm] = *(const bf16x8*)&lA[(wm * 64 + fm * 16 + rsel) * LDK + kgp];
#pragma unroll
        for (int fn = 0; fn < 4; ++fn)
            bfr[fn] = *(const bf16x8*)&lB[(wn * 64 + fn * 16 + rsel) * LDK + kgp];
#pragma unroll
        for (int fm = 0; fm < 4; ++fm)
#pragma unroll
            for (int fn = 0; fn < 4; ++fn)
                acc[fm][fn] = __builtin_amdgcn_mfma_f32_16x16x32_bf16(af[fm], bfr[fn], acc[fm][fn], 0, 0, 0);
    }
    const int ln15 = lane & 15, l4 = lane >> 4;
    int nidx[4], hwb[4];
#pragma unroll
    for (int fn = 0; fn < 4; ++fn) {
        int sb = s0 + wn * 64 + fn * 16;
        nidx[fn] = sb / HW; hwb[fn] = sb % HW;
    }
#pragma unroll
    for (int fm = 0; fm < 4; ++fm)
#pragma unroll
        for (int r = 0; r < 4; ++r) {
            const int o = bo + wm * 64 + fm * 16 + l4 * 4 + r;
            const float bvs = Bias[o];
#pragma unroll
            for (int fn = 0; fn < 4; ++fn)
                Out[(size_t)nidx[fn] * (OUT_C * HW) + o * HW + hwb[fn] + ln15] = acc[fm][fn][r] + bvs;
        }
}

extern "C" void kernel_launch(void* const* d_in, const int* in_sizes, int n_in,
                              void* d_out, int out_size, void* d_ws, size_t ws_size,
                              hipStream_t stream) {
    const float* x    = (const float*)d_in[0];
    const float* w    = (const float*)d_in[1];
    const float* bias = (const float*)d_in[2];
    float* out = (float*)d_out;

    if (ws_size >= WS_NEEDED) {
        char* xt = (char*)d_ws;
        char* wf = (char*)d_ws + XT_BYTES;
        conv_pre<<<3648, 256, 0, stream>>>(x, w, (u32x4*)xt, (u32x4*)wf);
        gemm_h<<<1568, 256, 0, stream>>>(wf, xt, bias, out);
    } else {
        dim3 grid(NHW / BN, OUT_C / BM);
        conv1x1_fallback<<<grid, 256, 0, stream>>>(x, w, bias, out);
    }
}

// Round 10
// 93.315 us; speedup vs baseline: 1.1102x; 1.1102x over previous
//
#include <hip/hip_runtime.h>

// SparseConv1x1 == GEMM: C[o,s] = W[o,:] . X[:,s] + b[o], s = n*784+hw
// M=1024, N=25088, K=1024, fp32 in/out, bf16 MFMA compute.
// Round 10 (convergence): round-8 keeper config (prepass at HBM floor +
// 2-phase 128^2 gemm at its structure ceiling) + safe micro-trims:
// bias prefetch before K-loop, skip final dead barrier.

#define IN_C   1024
#define OUT_C  1024
#define HW     784
#define NB     32
#define NHW    (NB * HW)                     // 25088
#define XT_BYTES ((size_t)NHW * IN_C * 2)    // 51,380,224
#define WB_BYTES ((size_t)OUT_C * IN_C * 2)  // 2,097,152
#define WS_NEEDED (XT_BYTES + WB_BYTES)
#define XSTR   (IN_C * HW)

typedef __bf16 bf16x8 __attribute__((ext_vector_type(8)));
typedef float  f32x4  __attribute__((ext_vector_type(4)));
typedef unsigned int u32x4 __attribute__((ext_vector_type(4)));

__device__ __forceinline__ unsigned int bfbits(float f) {
    unsigned int u = __float_as_uint(f);
    return (u + 0x8000u) >> 16;              // round-half-up fp32->bf16
}
__device__ __forceinline__ unsigned int packpair(float lo, float hi) {
    return bfbits(lo) | (bfbits(hi) << 16);
}
__device__ __forceinline__ void glds16(const void* g, void* l) {
    __builtin_amdgcn_global_load_lds(
        (const __attribute__((address_space(1))) void*)g,
        (__attribute__((address_space(3))) void*)l, 16, 0, 0);
}

// ---------- pre-pass: blocks [0,3136) transpose x (registerized), [3136,3648) convert W
__global__ __launch_bounds__(256)
void conv_pre(const float* __restrict__ X, const float* __restrict__ W,
              u32x4* __restrict__ Xt, u32x4* __restrict__ Wb)
{
    const int t = threadIdx.x;
    const int b = blockIdx.x;

    if (b >= 3136) {
        // W [1024][1024] f32 -> Wb bf16, unit-swizzled
        int gid = (b - 3136) * 256 + t;
        int o = gid >> 7;
        int u = gid & 127;
        const float* p = W + o * 1024 + u * 8;
        f32x4 a = *(const f32x4*)p;
        f32x4 c = *(const f32x4*)(p + 4);
        u32x4 r;
        r.x = packpair(a[0], a[1]); r.y = packpair(a[2], a[3]);
        r.z = packpair(c[0], c[1]); r.w = packpair(c[2], c[3]);
        Wb[o * 128 + (u ^ (o & 7))] = r;
        return;
    }

    // x-path: block = (s-tile of 128, k-chunk of 64); 3136 = 196 * 16
    const int c8   = b & 15;                 // k-chunk
    const int sblk = b >> 4;                 // s-tile
    const int kq8  = t & 7;                  // k-octet within chunk
    const int sc   = t >> 3;                 // 0..31: 4-s chunk
    const int sgl  = sblk * 128 + sc * 4;    // mult of 4; 784%4==0 -> same batch
    const int n    = sgl / HW, hw0 = sgl % HW;
    const float* xb = X + (size_t)n * XSTR + (size_t)(c8 * 64 + kq8 * 8) * HW + hw0;

    f32x4 v[8];
#pragma unroll
    for (int i = 0; i < 8; ++i)
        v[i] = *(const f32x4*)(xb + (size_t)i * HW);

#pragma unroll
    for (int j = 0; j < 4; ++j) {
        u32x4 wv;
        wv.x = packpair(v[0][j], v[1][j]);
        wv.y = packpair(v[2][j], v[3][j]);
        wv.z = packpair(v[4][j], v[5][j]);
        wv.w = packpair(v[6][j], v[7][j]);
        const int sl = sgl + j;
        Xt[(size_t)sl * 128 + c8 * 8 + (kq8 ^ (sl & 7))] = wv;
    }
}

// ---------- GEMM: proven 2-phase, 128x128 tile, BK=64, glds staging ----------
__global__ __launch_bounds__(256, 4)
void gemm_k(const char* __restrict__ Wb, const char* __restrict__ Xt,
            const float* __restrict__ Bias, float* __restrict__ Out)
{
    __shared__ __align__(16) char lA[128 * 128];  // [row][128B chunk], 16KB
    __shared__ __align__(16) char lB[128 * 128];

    const int t = threadIdx.x, lane = t & 63, wid = t >> 6;
    const int wm = wid >> 1, wn = wid & 1;

    // XCD swizzle: 8 o-blocks of one s-tile contiguous within an XCD
    const int bid = blockIdx.x;                   // 1568 = 8*196
    const int l   = (bid & 7) * 196 + (bid >> 3);
    const int bo  = (l & 7) * 128;
    const int s0  = (l >> 3) * 128;

    const char* ag = Wb + (size_t)(bo + wid * 32 + (lane >> 3)) * 2048 + (lane & 7) * 16;
    const char* bg = Xt + (size_t)(s0 + wid * 32 + (lane >> 3)) * 2048 + (lane & 7) * 16;
    char* la0 = &lA[(wid * 32) * 128];
    char* lb0 = &lB[(wid * 32) * 128];

    // bias prefetch: 16 per-lane values, issued before the K-loop (L2-hit hidden)
    const int l4 = lane >> 4;
    float bpre[4][4];
#pragma unroll
    for (int fm = 0; fm < 4; ++fm)
#pragma unroll
        for (int r = 0; r < 4; ++r)
            bpre[fm][r] = Bias[bo + wm * 64 + fm * 16 + l4 * 4 + r];

    f32x4 acc[4][4];
#pragma unroll
    for (int i = 0; i < 4; ++i)
#pragma unroll
        for (int j = 0; j < 4; ++j) acc[i][j] = 0.0f;

    const int rsel = lane & 15, kg = lane >> 4;

    for (int c = 0; c < 16; ++c) {                // K chunks of 64
        const int cb = c * 128;
#pragma unroll
        for (int i = 0; i < 4; ++i) {
            glds16(ag + (size_t)i * (8 * 2048) + cb, la0 + i * (8 * 128));
            glds16(bg + (size_t)i * (8 * 2048) + cb, lb0 + i * (8 * 128));
        }
        __syncthreads();   // drains vmcnt -> tiles ready (and all waves staged)

#pragma unroll
        for (int kk = 0; kk < 2; ++kk) {
            bf16x8 af[4], bv[4];
#pragma unroll
            for (int fm = 0; fm < 4; ++fm) {
                const int row = wm * 64 + fm * 16 + rsel;
                const int u   = (kk * 4 + kg) ^ (row & 7);
                af[fm] = *(const bf16x8*)&lA[row * 128 + u * 16];
            }
#pragma unroll
            for (int fn = 0; fn < 4; ++fn) {
                const int row = wn * 64 + fn * 16 + rsel;
                const int u   = (kk * 4 + kg) ^ (row & 7);
                bv[fn] = *(const bf16x8*)&lB[row * 128 + u * 16];
            }
#pragma unroll
            for (int fm = 0; fm < 4; ++fm)
#pragma unroll
                for (int fn = 0; fn < 4; ++fn)
                    acc[fm][fn] = __builtin_amdgcn_mfma_f32_16x16x32_bf16(
                        af[fm], bv[fn], acc[fm][fn], 0, 0, 0);
        }
        if (c < 15) __syncthreads();   // WAR guard; dead on last iteration
    }

    // epilogue: C/D layout col=lane&15, row=(lane>>4)*4+r
    const int ln15 = lane & 15;
    int nidx[4], hwb[4];
#pragma unroll
    for (int fn = 0; fn < 4; ++fn) {
        int sb = s0 + wn * 64 + fn * 16;          // 784%16==0 -> same batch per 16-run
        nidx[fn] = sb / HW;
        hwb[fn]  = sb % HW;
    }
#pragma unroll
    for (int fm = 0; fm < 4; ++fm) {
#pragma unroll
        for (int r = 0; r < 4; ++r) {
            const int o = bo + wm * 64 + fm * 16 + l4 * 4 + r;
            const float bvs = bpre[fm][r];
#pragma unroll
            for (int fn = 0; fn < 4; ++fn)
                Out[(size_t)nidx[fn] * (OUT_C * HW) + o * HW + hwb[fn] + ln15] =
                    acc[fm][fn][r] + bvs;
        }
    }
}

// ---------- fallback (round-1 kernel, used only if ws too small) ----------
#define BM 128
#define BN 128
#define LDK 40
__global__ __launch_bounds__(256, 2)
void conv1x1_fallback(const float* __restrict__ X, const float* __restrict__ W,
                      const float* __restrict__ Bias, float* __restrict__ Out)
{
    __shared__ __align__(16) unsigned short lA[BM * LDK];
    __shared__ __align__(16) unsigned short lB[BN * LDK];
    const int t = threadIdx.x, lane = t & 63, wid = t >> 6;
    const int wm = wid >> 1, wn = wid & 1;
    const int s0 = blockIdx.x * BN, bo = blockIdx.y * BM;
    const int kc4 = t & 7, r0 = t >> 3;
    const float* aptr = W + (bo + r0) * IN_C + kc4 * 4;
    const int kp = t & 15, sc = t >> 4;
    const int sglob = s0 + sc * 8;
    const int nbat = sglob / HW, hw0 = sglob % HW;
    const float* bptr = X + nbat * (IN_C * HW) + hw0;
    f32x4 acc[4][4];
#pragma unroll
    for (int i = 0; i < 4; ++i)
#pragma unroll
        for (int j = 0; j < 4; ++j) acc[i][j] = 0.0f;
    for (int k0 = 0; k0 < IN_C; k0 += 32) {
        f32x4 a[4];
#pragma unroll
        for (int i = 0; i < 4; ++i) a[i] = *(const f32x4*)(aptr + (i * 32) * IN_C + k0);
        const float* bp = bptr + (k0 + 2 * kp) * HW;
        f32x4 be0 = *(const f32x4*)(bp), be1 = *(const f32x4*)(bp + 4);
        f32x4 bo0 = *(const f32x4*)(bp + HW), bo1 = *(const f32x4*)(bp + HW + 4);
        __syncthreads();
#pragma unroll
        for (int i = 0; i < 4; ++i) {
            unsigned int w0 = packpair(a[i][0], a[i][1]);
            unsigned int w1 = packpair(a[i][2], a[i][3]);
            unsigned long long pq = ((unsigned long long)w1 << 32) | w0;
            *(unsigned long long*)&lA[(r0 + 32 * i) * LDK + kc4 * 4] = pq;
        }
#pragma unroll
        for (int c2 = 0; c2 < 2; ++c2) {
            const f32x4 ve = (c2 == 0) ? be0 : be1;
            const f32x4 vo = (c2 == 0) ? bo0 : bo1;
#pragma unroll
            for (int j = 0; j < 4; ++j)
                *(unsigned int*)&lB[(sc * 8 + c2 * 4 + j) * LDK + 2 * kp] = packpair(ve[j], vo[j]);
        }
        __syncthreads();
        bf16x8 af[4], bfr[4];
        const int rsel = lane & 15, kgp = (lane >> 4) * 8;
#pragma unroll
        for (int fm = 0; fm < 4; ++fm)
            af[fm] = *(const bf16x8*)&lA[(wm * 64 + fm * 16 + rsel) * LDK + kgp];
#pragma unroll
        for (int fn = 0; fn < 4; ++fn)
            bfr[fn] = *(const bf16x8*)&lB[(wn * 64 + fn * 16 + rsel) * LDK + kgp];
#pragma unroll
        for (int fm = 0; fm < 4; ++fm)
#pragma unroll
            for (int fn = 0; fn < 4; ++fn)
                acc[fm][fn] = __builtin_amdgcn_mfma_f32_16x16x32_bf16(af[fm], bfr[fn], acc[fm][fn], 0, 0, 0);
    }
    const int ln15 = lane & 15, l4 = lane >> 4;
    int nidx[4], hwb[4];
#pragma unroll
    for (int fn = 0; fn < 4; ++fn) {
        int sb = s0 + wn * 64 + fn * 16;
        nidx[fn] = sb / HW; hwb[fn] = sb % HW;
    }
#pragma unroll
    for (int fm = 0; fm < 4; ++fm)
#pragma unroll
        for (int r = 0; r < 4; ++r) {
            const int o = bo + wm * 64 + fm * 16 + l4 * 4 + r;
            const float bvs = Bias[o];
#pragma unroll
            for (int fn = 0; fn < 4; ++fn)
                Out[(size_t)nidx[fn] * (OUT_C * HW) + o * HW + hwb[fn] + ln15] = acc[fm][fn][r] + bvs;
        }
}

extern "C" void kernel_launch(void* const* d_in, const int* in_sizes, int n_in,
                              void* d_out, int out_size, void* d_ws, size_t ws_size,
                              hipStream_t stream) {
    const float* x    = (const float*)d_in[0];
    const float* w    = (const float*)d_in[1];
    const float* bias = (const float*)d_in[2];
    float* out = (float*)d_out;

    if (ws_size >= WS_NEEDED) {
        char* xt = (char*)d_ws;
        char* wb = (char*)d_ws + XT_BYTES;
        conv_pre<<<3648, 256, 0, stream>>>(x, w, (u32x4*)xt, (u32x4*)wb);
        gemm_k<<<1568, 256, 0, stream>>>(wb, xt, bias, out);
    } else {
        dim3 grid(NHW / BN, OUT_C / BM);
        conv1x1_fallback<<<grid, 256, 0, stream>>>(x, w, bias, out);
    }
}

// Round 11
// 91.486 us; speedup vs baseline: 1.1324x; 1.0200x over previous
//
#include <hip/hip_runtime.h>

// SparseConv1x1 == GEMM: C[o,s] = W[o,:] . X[:,s] + b[o], s = n*784+hw
// M=1024, N=25088, K=1024, fp32 in/out, bf16 MFMA compute.
// Round 11 (final convergence): exact round-8 configuration — the measured best
// (91.7us). Prepass at 92% of HBM floor; 2-phase 128^2 gemm at the m97-structure
// ceiling (843 TF, reproduced 5x). Round-10 micro-trims reverted (both regressed:
// +VGPR pressure, +8% WRITE_SIZE from staggered epilogues).

#define IN_C   1024
#define OUT_C  1024
#define HW     784
#define NB     32
#define NHW    (NB * HW)                     // 25088
#define XT_BYTES ((size_t)NHW * IN_C * 2)    // 51,380,224
#define WB_BYTES ((size_t)OUT_C * IN_C * 2)  // 2,097,152
#define WS_NEEDED (XT_BYTES + WB_BYTES)
#define XSTR   (IN_C * HW)

typedef __bf16 bf16x8 __attribute__((ext_vector_type(8)));
typedef float  f32x4  __attribute__((ext_vector_type(4)));
typedef unsigned int u32x4 __attribute__((ext_vector_type(4)));

__device__ __forceinline__ unsigned int bfbits(float f) {
    unsigned int u = __float_as_uint(f);
    return (u + 0x8000u) >> 16;              // round-half-up fp32->bf16
}
__device__ __forceinline__ unsigned int packpair(float lo, float hi) {
    return bfbits(lo) | (bfbits(hi) << 16);
}
__device__ __forceinline__ void glds16(const void* g, void* l) {
    __builtin_amdgcn_global_load_lds(
        (const __attribute__((address_space(1))) void*)g,
        (__attribute__((address_space(3))) void*)l, 16, 0, 0);
}

// ---------- pre-pass: blocks [0,3136) transpose x (registerized), [3136,3648) convert W
// x-path thread (kq8 = t&7, sc = t>>3): 8 k-strided f32x4 loads covering
// (8 k) x (4 s); pack to bf16; 4 swizzled 16B stores (one per s-row).
__global__ __launch_bounds__(256)
void conv_pre(const float* __restrict__ X, const float* __restrict__ W,
              u32x4* __restrict__ Xt, u32x4* __restrict__ Wb)
{
    const int t = threadIdx.x;
    const int b = blockIdx.x;

    if (b >= 3136) {
        // W [1024][1024] f32 -> Wb bf16, unit-swizzled
        int gid = (b - 3136) * 256 + t;
        int o = gid >> 7;
        int u = gid & 127;
        const float* p = W + o * 1024 + u * 8;
        f32x4 a = *(const f32x4*)p;
        f32x4 c = *(const f32x4*)(p + 4);
        u32x4 r;
        r.x = packpair(a[0], a[1]); r.y = packpair(a[2], a[3]);
        r.z = packpair(c[0], c[1]); r.w = packpair(c[2], c[3]);
        Wb[o * 128 + (u ^ (o & 7))] = r;
        return;
    }

    // x-path: block = (s-tile of 128, k-chunk of 64); 3136 = 196 * 16
    const int c8   = b & 15;                 // k-chunk
    const int sblk = b >> 4;                 // s-tile
    const int kq8  = t & 7;                  // k-octet within chunk
    const int sc   = t >> 3;                 // 0..31: 4-s chunk
    const int sgl  = sblk * 128 + sc * 4;    // mult of 4; 784%4==0 -> same batch
    const int n    = sgl / HW, hw0 = sgl % HW;
    const float* xb = X + (size_t)n * XSTR + (size_t)(c8 * 64 + kq8 * 8) * HW + hw0;

    f32x4 v[8];
#pragma unroll
    for (int i = 0; i < 8; ++i)
        v[i] = *(const f32x4*)(xb + (size_t)i * HW);

#pragma unroll
    for (int j = 0; j < 4; ++j) {
        u32x4 wv;
        wv.x = packpair(v[0][j], v[1][j]);
        wv.y = packpair(v[2][j], v[3][j]);
        wv.z = packpair(v[4][j], v[5][j]);
        wv.w = packpair(v[6][j], v[7][j]);
        const int sl = sgl + j;
        Xt[(size_t)sl * 128 + c8 * 8 + (kq8 ^ (sl & 7))] = wv;
    }
}

// ---------- GEMM: proven 2-phase, 128x128 tile, BK=64, glds staging ----------
__global__ __launch_bounds__(256, 4)
void gemm_k(const char* __restrict__ Wb, const char* __restrict__ Xt,
            const float* __restrict__ Bias, float* __restrict__ Out)
{
    __shared__ __align__(16) char lA[128 * 128];  // [row][128B chunk], 16KB
    __shared__ __align__(16) char lB[128 * 128];

    const int t = threadIdx.x, lane = t & 63, wid = t >> 6;
    const int wm = wid >> 1, wn = wid & 1;

    // XCD swizzle: 8 o-blocks of one s-tile contiguous within an XCD
    const int bid = blockIdx.x;                   // 1568 = 8*196
    const int l   = (bid & 7) * 196 + (bid >> 3);
    const int bo  = (l & 7) * 128;
    const int s0  = (l >> 3) * 128;

    const char* ag = Wb + (size_t)(bo + wid * 32 + (lane >> 3)) * 2048 + (lane & 7) * 16;
    const char* bg = Xt + (size_t)(s0 + wid * 32 + (lane >> 3)) * 2048 + (lane & 7) * 16;
    char* la0 = &lA[(wid * 32) * 128];
    char* lb0 = &lB[(wid * 32) * 128];

    f32x4 acc[4][4];
#pragma unroll
    for (int i = 0; i < 4; ++i)
#pragma unroll
        for (int j = 0; j < 4; ++j) acc[i][j] = 0.0f;

    const int rsel = lane & 15, kg = lane >> 4;

    for (int c = 0; c < 16; ++c) {                // K chunks of 64
        const int cb = c * 128;
#pragma unroll
        for (int i = 0; i < 4; ++i) {
            glds16(ag + (size_t)i * (8 * 2048) + cb, la0 + i * (8 * 128));
            glds16(bg + (size_t)i * (8 * 2048) + cb, lb0 + i * (8 * 128));
        }
        __syncthreads();   // drains vmcnt -> tiles ready (and all waves staged)

#pragma unroll
        for (int kk = 0; kk < 2; ++kk) {
            bf16x8 af[4], bv[4];
#pragma unroll
            for (int fm = 0; fm < 4; ++fm) {
                const int row = wm * 64 + fm * 16 + rsel;
                const int u   = (kk * 4 + kg) ^ (row & 7);
                af[fm] = *(const bf16x8*)&lA[row * 128 + u * 16];
            }
#pragma unroll
            for (int fn = 0; fn < 4; ++fn) {
                const int row = wn * 64 + fn * 16 + rsel;
                const int u   = (kk * 4 + kg) ^ (row & 7);
                bv[fn] = *(const bf16x8*)&lB[row * 128 + u * 16];
            }
#pragma unroll
            for (int fm = 0; fm < 4; ++fm)
#pragma unroll
                for (int fn = 0; fn < 4; ++fn)
                    acc[fm][fn] = __builtin_amdgcn_mfma_f32_16x16x32_bf16(
                        af[fm], bv[fn], acc[fm][fn], 0, 0, 0);
        }
        __syncthreads();   // all reads done before next stage overwrites
    }

    // epilogue: C/D layout col=lane&15, row=(lane>>4)*4+r
    const int ln15 = lane & 15, l4 = lane >> 4;
    int nidx[4], hwb[4];
#pragma unroll
    for (int fn = 0; fn < 4; ++fn) {
        int sb = s0 + wn * 64 + fn * 16;          // 784%16==0 -> same batch per 16-run
        nidx[fn] = sb / HW;
        hwb[fn]  = sb % HW;
    }
#pragma unroll
    for (int fm = 0; fm < 4; ++fm) {
#pragma unroll
        for (int r = 0; r < 4; ++r) {
            const int o = bo + wm * 64 + fm * 16 + l4 * 4 + r;
            const float bvs = Bias[o];
#pragma unroll
            for (int fn = 0; fn < 4; ++fn)
                Out[(size_t)nidx[fn] * (OUT_C * HW) + o * HW + hwb[fn] + ln15] =
                    acc[fm][fn][r] + bvs;
        }
    }
}

// ---------- fallback (round-1 kernel, used only if ws too small) ----------
#define BM 128
#define BN 128
#define LDK 40
__global__ __launch_bounds__(256, 2)
void conv1x1_fallback(const float* __restrict__ X, const float* __restrict__ W,
                      const float* __restrict__ Bias, float* __restrict__ Out)
{
    __shared__ __align__(16) unsigned short lA[BM * LDK];
    __shared__ __align__(16) unsigned short lB[BN * LDK];
    const int t = threadIdx.x, lane = t & 63, wid = t >> 6;
    const int wm = wid >> 1, wn = wid & 1;
    const int s0 = blockIdx.x * BN, bo = blockIdx.y * BM;
    const int kc4 = t & 7, r0 = t >> 3;
    const float* aptr = W + (bo + r0) * IN_C + kc4 * 4;
    const int kp = t & 15, sc = t >> 4;
    const int sglob = s0 + sc * 8;
    const int nbat = sglob / HW, hw0 = sglob % HW;
    const float* bptr = X + nbat * (IN_C * HW) + hw0;
    f32x4 acc[4][4];
#pragma unroll
    for (int i = 0; i < 4; ++i)
#pragma unroll
        for (int j = 0; j < 4; ++j) acc[i][j] = 0.0f;
    for (int k0 = 0; k0 < IN_C; k0 += 32) {
        f32x4 a[4];
#pragma unroll
        for (int i = 0; i < 4; ++i) a[i] = *(const f32x4*)(aptr + (i * 32) * IN_C + k0);
        const float* bp = bptr + (k0 + 2 * kp) * HW;
        f32x4 be0 = *(const f32x4*)(bp), be1 = *(const f32x4*)(bp + 4);
        f32x4 bo0 = *(const f32x4*)(bp + HW), bo1 = *(const f32x4*)(bp + HW + 4);
        __syncthreads();
#pragma unroll
        for (int i = 0; i < 4; ++i) {
            unsigned int w0 = packpair(a[i][0], a[i][1]);
            unsigned int w1 = packpair(a[i][2], a[i][3]);
            unsigned long long pq = ((unsigned long long)w1 << 32) | w0;
            *(unsigned long long*)&lA[(r0 + 32 * i) * LDK + kc4 * 4] = pq;
        }
#pragma unroll
        for (int c2 = 0; c2 < 2; ++c2) {
            const f32x4 ve = (c2 == 0) ? be0 : be1;
            const f32x4 vo = (c2 == 0) ? bo0 : bo1;
#pragma unroll
            for (int j = 0; j < 4; ++j)
                *(unsigned int*)&lB[(sc * 8 + c2 * 4 + j) * LDK + 2 * kp] = packpair(ve[j], vo[j]);
        }
        __syncthreads();
        bf16x8 af[4], bfr[4];
        const int rsel = lane & 15, kgp = (lane >> 4) * 8;
#pragma unroll
        for (int fm = 0; fm < 4; ++fm)
            af[fm] = *(const bf16x8*)&lA[(wm * 64 + fm * 16 + rsel) * LDK + kgp];
#pragma unroll
        for (int fn = 0; fn < 4; ++fn)
            bfr[fn] = *(const bf16x8*)&lB[(wn * 64 + fn * 16 + rsel) * LDK + kgp];
#pragma unroll
        for (int fm = 0; fm < 4; ++fm)
#pragma unroll
            for (int fn = 0; fn < 4; ++fn)
                acc[fm][fn] = __builtin_amdgcn_mfma_f32_16x16x32_bf16(af[fm], bfr[fn], acc[fm][fn], 0, 0, 0);
    }
    const int ln15 = lane & 15, l4 = lane >> 4;
    int nidx[4], hwb[4];
#pragma unroll
    for (int fn = 0; fn < 4; ++fn) {
        int sb = s0 + wn * 64 + fn * 16;
        nidx[fn] = sb / HW; hwb[fn] = sb % HW;
    }
#pragma unroll
    for (int fm = 0; fm < 4; ++fm)
#pragma unroll
        for (int r = 0; r < 4; ++r) {
            const int o = bo + wm * 64 + fm * 16 + l4 * 4 + r;
            const float bvs = Bias[o];
#pragma unroll
            for (int fn = 0; fn < 4; ++fn)
                Out[(size_t)nidx[fn] * (OUT_C * HW) + o * HW + hwb[fn] + ln15] = acc[fm][fn][r] + bvs;
        }
}

extern "C" void kernel_launch(void* const* d_in, const int* in_sizes, int n_in,
                              void* d_out, int out_size, void* d_ws, size_t ws_size,
                              hipStream_t stream) {
    const float* x    = (const float*)d_in[0];
    const float* w    = (const float*)d_in[1];
    const float* bias = (const float*)d_in[2];
    float* out = (float*)d_out;

    if (ws_size >= WS_NEEDED) {
        char* xt = (char*)d_ws;
        char* wb = (char*)d_ws + XT_BYTES;
        conv_pre<<<3648, 256, 0, stream>>>(x, w, (u32x4*)xt, (u32x4*)wb);
        gemm_k<<<1568, 256, 0, stream>>>(wb, xt, bias, out);
    } else {
        dim3 grid(NHW / BN, OUT_C / BM);
        conv1x1_fallback<<<grid, 256, 0, stream>>>(x, w, bias, out);
    }
}